// Round 1
// baseline (954.109 us; speedup 1.0000x reference)
//
#include <hip/hip_runtime.h>
#include <math.h>

#define NEG_SLOPE 0.2f
#define EPSF 1e-16f

constexpr int FIN = 128;
constexpr int H   = 64;
constexpr int C   = 2;

// ---------- scalar precompute ----------
__global__ void ea_sum_kernel(const float* __restrict__ ea, int E, float* __restrict__ out) {
    float acc = 0.f;
    for (int i = blockIdx.x * blockDim.x + threadIdx.x; i < E; i += gridDim.x * blockDim.x)
        acc += ea[i];
    for (int off = 32; off; off >>= 1) acc += __shfl_down(acc, off, 64);
    __shared__ float wsum[4];
    int lane = threadIdx.x & 63, wv = threadIdx.x >> 6;
    if (lane == 0) wsum[wv] = acc;
    __syncthreads();
    if (threadIdx.x == 0) atomicAdd(out, wsum[0] + wsum[1] + wsum[2] + wsum[3]);
}

__global__ void scalars_kernel(const float* __restrict__ sum_ea, int E,
                               const float* __restrict__ W_edge1, const float* __restrict__ att_edge1,
                               const float* __restrict__ W_edge2, const float* __restrict__ att_edge2,
                               float* __restrict__ out3) {
    if (threadIdx.x == 0) {
        float m = *sum_ea / (float)E;
        float c1 = 0.f;
        for (int i = 0; i < H; i++) c1 += W_edge1[i] * att_edge1[i];
        float c2 = 0.f;
        for (int i = 0; i < C; i++) c2 += W_edge2[i] * att_edge2[i];
        out3[0] = m; out3[1] = c1; out3[2] = c2;
    }
}

// ---------- layer 1 GEMM + per-node logits ----------
#define NPB 8
__global__ __launch_bounds__(512) void gemm1_kernel(
        const float* __restrict__ x, const float* __restrict__ W1,
        const float* __restrict__ att_src, const float* __restrict__ att_dst,
        float* __restrict__ h1, float* __restrict__ a_s, float* __restrict__ a_d, int N) {
    __shared__ float sW[FIN * H];      // 32 KB
    __shared__ float sx[NPB][FIN];     // 4 KB
    int tid = threadIdx.x;
    for (int i = tid; i < FIN * H; i += 512) sW[i] = W1[i];
    int node0 = blockIdx.x * NPB;
    for (int i = tid; i < NPB * FIN; i += 512) {
        int n = node0 + i / FIN;
        sx[i / FIN][i % FIN] = (n < N) ? x[(size_t)n * FIN + (i % FIN)] : 0.f;
    }
    __syncthreads();
    int wv = tid >> 6;      // node within block
    int lane = tid & 63;    // output feature
    int n = node0 + wv;
    if (n >= N) return;
    const float* xr = sx[wv];
    float acc = 0.f;
    #pragma unroll 8
    for (int k = 0; k < FIN; k++) acc += xr[k] * sW[k * H + lane];
    h1[(size_t)n * H + lane] = acc;
    float ps = acc * att_src[lane];
    float pd = acc * att_dst[lane];
    for (int off = 32; off; off >>= 1) {
        ps += __shfl_down(ps, off, 64);
        pd += __shfl_down(pd, off, 64);
    }
    if (lane == 0) { a_s[n] = ps; a_d[n] = pd; }
}

// ---------- layer 1 edge pass: wave per edge ----------
__global__ __launch_bounds__(256) void edge1_kernel(
        const int* __restrict__ src, const int* __restrict__ dst,
        const float* __restrict__ ea, const float* __restrict__ scal,
        const float* __restrict__ a_s, const float* __restrict__ a_d,
        const float* __restrict__ h1, float* __restrict__ S1, float* __restrict__ denom,
        int E, int N) {
    int wid = (blockIdx.x * blockDim.x + threadIdx.x) >> 6;  // edge id
    int lane = threadIdx.x & 63;
    int Et = E + N;
    if (wid >= Et) return;
    float c1 = scal[1];
    int s, d; float aeterm;
    if (wid < E) { s = src[wid]; d = dst[wid]; aeterm = ea[wid] * c1; }
    else         { s = wid - E;  d = s;        aeterm = scal[0] * c1; }
    float logit = a_s[s] + a_d[d] + aeterm;
    logit = (logit > 0.f) ? logit : NEG_SLOPE * logit;
    float ex = __expf(logit);
    atomicAdd(&S1[(size_t)d * H + lane], ex * h1[(size_t)s * H + lane]);
    if (lane == 0) atomicAdd(&denom[d], ex);
}

// ---------- layer 1 finalize: divide, bias, relu ----------
__global__ void node1_kernel(const float* __restrict__ S1, const float* __restrict__ denom,
                             const float* __restrict__ bias, float* __restrict__ hr, int N) {
    int i = blockIdx.x * blockDim.x + threadIdx.x;
    if (i >= N * H) return;
    int n = i >> 6, f = i & 63;
    float v = S1[i] / (denom[n] + EPSF) + bias[f];
    hr[i] = v > 0.f ? v : 0.f;
}

// ---------- layer 2 GEMM (64->2): wave per node ----------
__global__ __launch_bounds__(256) void gemm2_kernel(
        const float* __restrict__ hr, const float* __restrict__ W2,
        const float* __restrict__ att_src2, const float* __restrict__ att_dst2,
        float* __restrict__ h2, float* __restrict__ a_s2, float* __restrict__ a_d2, int N) {
    int wid = (blockIdx.x * blockDim.x + threadIdx.x) >> 6;
    int lane = threadIdx.x & 63;
    if (wid >= N) return;
    float hv = hr[(size_t)wid * H + lane];
    float p0 = hv * W2[lane * C + 0];
    float p1 = hv * W2[lane * C + 1];
    for (int off = 32; off; off >>= 1) {
        p0 += __shfl_down(p0, off, 64);
        p1 += __shfl_down(p1, off, 64);
    }
    if (lane == 0) {
        h2[(size_t)wid * C + 0] = p0;
        h2[(size_t)wid * C + 1] = p1;
        a_s2[wid] = p0 * att_src2[0] + p1 * att_src2[1];
        a_d2[wid] = p0 * att_dst2[0] + p1 * att_dst2[1];
    }
}

// ---------- layer 2 edge pass: thread per edge ----------
__global__ void edge2_kernel(const int* __restrict__ src, const int* __restrict__ dst,
                             const float* __restrict__ ea, const float* __restrict__ scal,
                             const float* __restrict__ a_s2, const float* __restrict__ a_d2,
                             const float* __restrict__ h2, float* __restrict__ S2,
                             float* __restrict__ denom2, int E, int N) {
    int e = blockIdx.x * blockDim.x + threadIdx.x;
    int Et = E + N;
    if (e >= Et) return;
    float c2 = scal[2];
    int s, d; float aeterm;
    if (e < E) { s = src[e]; d = dst[e]; aeterm = ea[e] * c2; }
    else       { s = e - E;  d = s;      aeterm = scal[0] * c2; }
    float logit = a_s2[s] + a_d2[d] + aeterm;
    logit = (logit > 0.f) ? logit : NEG_SLOPE * logit;
    float ex = __expf(logit);
    atomicAdd(&S2[(size_t)d * C + 0], ex * h2[(size_t)s * C + 0]);
    atomicAdd(&S2[(size_t)d * C + 1], ex * h2[(size_t)s * C + 1]);
    atomicAdd(&denom2[d], ex);
}

// ---------- layer 2 finalize + log_softmax ----------
__global__ void node2_kernel(const float* __restrict__ S2, const float* __restrict__ denom2,
                             const float* __restrict__ bias2, float* __restrict__ out, int N) {
    int n = blockIdx.x * blockDim.x + threadIdx.x;
    if (n >= N) return;
    float dn = denom2[n] + EPSF;
    float o0 = S2[(size_t)n * C + 0] / dn + bias2[0];
    float o1 = S2[(size_t)n * C + 1] / dn + bias2[1];
    float m = fmaxf(o0, o1);
    float lse = m + logf(expf(o0 - m) + expf(o1 - m));
    out[(size_t)n * C + 0] = o0 - lse;
    out[(size_t)n * C + 1] = o1 - lse;
}

extern "C" void kernel_launch(void* const* d_in, const int* in_sizes, int n_in,
                              void* d_out, int out_size, void* d_ws, size_t ws_size,
                              hipStream_t stream) {
    const float* x        = (const float*)d_in[0];
    const int*   ei       = (const int*)d_in[1];
    const float* ea       = (const float*)d_in[2];
    const float* W1       = (const float*)d_in[3];
    const float* att_src1 = (const float*)d_in[4];
    const float* att_dst1 = (const float*)d_in[5];
    const float* W_edge1  = (const float*)d_in[6];
    const float* att_edge1= (const float*)d_in[7];
    const float* bias1    = (const float*)d_in[8];
    const float* W2       = (const float*)d_in[9];
    const float* att_src2 = (const float*)d_in[10];
    const float* att_dst2 = (const float*)d_in[11];
    const float* W_edge2  = (const float*)d_in[12];
    const float* att_edge2= (const float*)d_in[13];
    const float* bias2    = (const float*)d_in[14];

    const int N  = in_sizes[0] / FIN;
    const int E  = in_sizes[1] / 2;
    const int Et = E + N;
    const int* srcp = ei;
    const int* dstp = ei + E;

    float* ws = (float*)d_ws;
    size_t off = 0;
    float* S1     = ws + off; off += (size_t)N * H;
    float* denom1 = ws + off; off += N;
    float* S2     = ws + off; off += (size_t)N * C;
    float* denom2 = ws + off; off += N;
    float* sum_ea = ws + off; off += 1;
    size_t zcount = off;                     // region that must be zero
    float* h1     = ws + off; off += (size_t)N * H;
    float* a_s1   = ws + off; off += N;
    float* a_d1   = ws + off; off += N;
    float* h2     = ws + off; off += (size_t)N * C;
    float* a_s2   = ws + off; off += N;
    float* a_d2   = ws + off; off += N;
    float* scal   = ws + off; off += 3;

    hipMemsetAsync(d_ws, 0, zcount * sizeof(float), stream);

    ea_sum_kernel<<<1024, 256, 0, stream>>>(ea, E, sum_ea);
    scalars_kernel<<<1, 64, 0, stream>>>(sum_ea, E, W_edge1, att_edge1, W_edge2, att_edge2, scal);
    gemm1_kernel<<<(N + NPB - 1) / NPB, 512, 0, stream>>>(x, W1, att_src1, att_dst1, h1, a_s1, a_d1, N);
    edge1_kernel<<<(Et + 3) / 4, 256, 0, stream>>>(srcp, dstp, ea, scal, a_s1, a_d1, h1, S1, denom1, E, N);
    node1_kernel<<<((size_t)N * H + 255) / 256, 256, 0, stream>>>(S1, denom1, bias1, h1, N);
    gemm2_kernel<<<(N + 3) / 4, 256, 0, stream>>>(h1, W2, att_src2, att_dst2, h2, a_s2, a_d2, N);
    edge2_kernel<<<(Et + 255) / 256, 256, 0, stream>>>(srcp, dstp, ea, scal, a_s2, a_d2, h2, S2, denom2, E, N);
    node2_kernel<<<(N + 255) / 256, 256, 0, stream>>>(S2, denom2, bias2, (float*)d_out, N);
}

// Round 2
// 767.471 us; speedup vs baseline: 1.2432x; 1.2432x over previous
//
#include <hip/hip_runtime.h>
#include <math.h>

#define NEG_SLOPE 0.2f
#define EPSF 1e-16f

constexpr int FIN = 128;
constexpr int H   = 64;
constexpr int C   = 2;

// ---------- scalar precompute ----------
__global__ void ea_sum_kernel(const float* __restrict__ ea, int E, float* __restrict__ out) {
    float acc = 0.f;
    for (int i = blockIdx.x * blockDim.x + threadIdx.x; i < E; i += gridDim.x * blockDim.x)
        acc += ea[i];
    for (int off = 32; off; off >>= 1) acc += __shfl_down(acc, off, 64);
    __shared__ float wsum[4];
    int lane = threadIdx.x & 63, wv = threadIdx.x >> 6;
    if (lane == 0) wsum[wv] = acc;
    __syncthreads();
    if (threadIdx.x == 0) atomicAdd(out, wsum[0] + wsum[1] + wsum[2] + wsum[3]);
}

__global__ void scalars_kernel(const float* __restrict__ sum_ea, int E,
                               const float* __restrict__ W_edge1, const float* __restrict__ att_edge1,
                               const float* __restrict__ W_edge2, const float* __restrict__ att_edge2,
                               float* __restrict__ out3) {
    if (threadIdx.x == 0) {
        float m = *sum_ea / (float)E;
        float c1 = 0.f;
        for (int i = 0; i < H; i++) c1 += W_edge1[i] * att_edge1[i];
        float c2 = 0.f;
        for (int i = 0; i < C; i++) c2 += W_edge2[i] * att_edge2[i];
        out3[0] = m; out3[1] = c1; out3[2] = c2;
    }
}

// ---------- CSR build: histogram of dst ----------
__global__ void hist_kernel(const int* __restrict__ dst, int E, int* __restrict__ hist) {
    int e = blockIdx.x * blockDim.x + threadIdx.x;
    if (e < E) atomicAdd(&hist[dst[e]], 1);
}

// ---------- CSR build: single-block exclusive scan of hist -> row, cursor ----------
__global__ __launch_bounds__(1024) void scan_kernel(const int* __restrict__ hist,
                                                    int* __restrict__ row, int* __restrict__ cursor,
                                                    int N) {
    __shared__ int tsum[1024];
    int t = threadIdx.x;
    int chunk = (N + 1023) / 1024;
    int lo = t * chunk, hi = min(lo + chunk, N);
    int s = 0;
    for (int i = lo; i < hi; i++) s += hist[i];
    tsum[t] = s;
    __syncthreads();
    for (int off = 1; off < 1024; off <<= 1) {
        int v = (t >= off) ? tsum[t - off] : 0;
        __syncthreads();
        if (t >= off) tsum[t] += v;
        __syncthreads();
    }
    int run = (t == 0) ? 0 : tsum[t - 1];
    for (int i = lo; i < hi; i++) {
        row[i] = run; cursor[i] = run;
        run += hist[i];
    }
    if (t == 1023) row[N] = run;
}

// ---------- CSR build: scatter edges into dst-sorted order ----------
__global__ void scatter_kernel(const int* __restrict__ src, const int* __restrict__ dst,
                               const float* __restrict__ ea, int E,
                               int* __restrict__ cursor,
                               int* __restrict__ ssrc, float* __restrict__ sea) {
    int e = blockIdx.x * blockDim.x + threadIdx.x;
    if (e >= E) return;
    int d = dst[e];
    int pos = atomicAdd(&cursor[d], 1);
    ssrc[pos] = src[e];
    sea[pos]  = ea[e];
}

// ---------- layer 1 GEMM + per-node logits ----------
#define NPB 8
__global__ __launch_bounds__(512) void gemm1_kernel(
        const float* __restrict__ x, const float* __restrict__ W1,
        const float* __restrict__ att_src, const float* __restrict__ att_dst,
        float* __restrict__ h1, float* __restrict__ a_s, float* __restrict__ a_d, int N) {
    __shared__ float sW[FIN * H];      // 32 KB
    __shared__ float sx[NPB][FIN];     // 4 KB
    int tid = threadIdx.x;
    for (int i = tid; i < FIN * H; i += 512) sW[i] = W1[i];
    int node0 = blockIdx.x * NPB;
    for (int i = tid; i < NPB * FIN; i += 512) {
        int n = node0 + i / FIN;
        sx[i / FIN][i % FIN] = (n < N) ? x[(size_t)n * FIN + (i % FIN)] : 0.f;
    }
    __syncthreads();
    int wv = tid >> 6;
    int lane = tid & 63;
    int n = node0 + wv;
    if (n >= N) return;
    const float* xr = sx[wv];
    float acc = 0.f;
    #pragma unroll 8
    for (int k = 0; k < FIN; k++) acc += xr[k] * sW[k * H + lane];
    h1[(size_t)n * H + lane] = acc;
    float ps = acc * att_src[lane];
    float pd = acc * att_dst[lane];
    for (int off = 32; off; off >>= 1) {
        ps += __shfl_down(ps, off, 64);
        pd += __shfl_down(pd, off, 64);
    }
    if (lane == 0) { a_s[n] = ps; a_d[n] = pd; }
}

// ---------- layer 1 aggregation (wave per dst node) + node1 + gemm2 fused ----------
__global__ __launch_bounds__(256) void agg1_kernel(
        const int* __restrict__ row, const int* __restrict__ ssrc, const float* __restrict__ sea,
        const float* __restrict__ scal,
        const float* __restrict__ a_s, const float* __restrict__ a_d,
        const float* __restrict__ h1,
        const float* __restrict__ bias1, const float* __restrict__ W2,
        const float* __restrict__ att_src2, const float* __restrict__ att_dst2,
        float* __restrict__ h2, float* __restrict__ a_s2, float* __restrict__ a_d2,
        int N) {
    int n = (blockIdx.x << 2) + (threadIdx.x >> 6);   // dst node
    int lane = threadIdx.x & 63;
    if (n >= N) return;
    float c1 = scal[1];
    float ad = a_d[n];
    int beg = row[n], end = row[n + 1];
    float den = 0.f, acc = 0.f;
    int i = beg;
    // 2x unrolled main loop to pipeline the dependent scalar gathers
    for (; i + 2 <= end; i += 2) {
        int s0 = ssrc[i], s1 = ssrc[i + 1];
        float ae0 = sea[i] * c1, ae1 = sea[i + 1] * c1;
        float as0 = a_s[s0], as1 = a_s[s1];
        float h0 = h1[(size_t)s0 * H + lane];
        float hv1 = h1[(size_t)s1 * H + lane];
        float lg0 = as0 + ad + ae0; lg0 = lg0 > 0.f ? lg0 : NEG_SLOPE * lg0;
        float lg1 = as1 + ad + ae1; lg1 = lg1 > 0.f ? lg1 : NEG_SLOPE * lg1;
        float e0 = __expf(lg0), e1 = __expf(lg1);
        den += e0 + e1;
        acc += e0 * h0 + e1 * hv1;
    }
    for (; i < end; i++) {
        int s = ssrc[i];
        float lg = a_s[s] + ad + sea[i] * c1;
        lg = lg > 0.f ? lg : NEG_SLOPE * lg;
        float ex = __expf(lg);
        den += ex;
        acc += ex * h1[(size_t)s * H + lane];
    }
    // self loop (src = dst = n, edge_attr = mean)
    {
        float lg = a_s[n] + ad + scal[0] * c1;
        lg = lg > 0.f ? lg : NEG_SLOPE * lg;
        float ex = __expf(lg);
        den += ex;
        acc += ex * h1[(size_t)n * H + lane];
    }
    float hr = acc / (den + EPSF) + bias1[lane];
    hr = fmaxf(hr, 0.f);
    // fused gemm2: h2 = hr @ W2  (64 -> 2)
    float p0 = hr * W2[lane * C + 0];
    float p1 = hr * W2[lane * C + 1];
    for (int off = 32; off; off >>= 1) {
        p0 += __shfl_down(p0, off, 64);
        p1 += __shfl_down(p1, off, 64);
    }
    if (lane == 0) {
        h2[(size_t)n * C + 0] = p0;
        h2[(size_t)n * C + 1] = p1;
        a_s2[n] = p0 * att_src2[0] + p1 * att_src2[1];
        a_d2[n] = p0 * att_dst2[0] + p1 * att_dst2[1];
    }
}

// ---------- layer 2 aggregation (wave per dst node, lanes over edges) + log_softmax ----------
__global__ __launch_bounds__(256) void agg2_kernel(
        const int* __restrict__ row, const int* __restrict__ ssrc, const float* __restrict__ sea,
        const float* __restrict__ scal,
        const float* __restrict__ a_s2, const float* __restrict__ a_d2,
        const float* __restrict__ h2, const float* __restrict__ bias2,
        float* __restrict__ out, int N) {
    int n = (blockIdx.x << 2) + (threadIdx.x >> 6);
    int lane = threadIdx.x & 63;
    if (n >= N) return;
    float c2 = scal[2];
    float ad = a_d2[n];
    int beg = row[n], end = row[n + 1];
    float den = 0.f, m0 = 0.f, m1 = 0.f;
    for (int i = beg + lane; i < end; i += 64) {
        int s = ssrc[i];
        float lg = a_s2[s] + ad + sea[i] * c2;
        lg = lg > 0.f ? lg : NEG_SLOPE * lg;
        float ex = __expf(lg);
        den += ex;
        m0 += ex * h2[(size_t)s * C + 0];
        m1 += ex * h2[(size_t)s * C + 1];
    }
    if (lane == 0) {   // self loop
        float lg = a_s2[n] + ad + scal[0] * c2;
        lg = lg > 0.f ? lg : NEG_SLOPE * lg;
        float ex = __expf(lg);
        den += ex;
        m0 += ex * h2[(size_t)n * C + 0];
        m1 += ex * h2[(size_t)n * C + 1];
    }
    for (int off = 32; off; off >>= 1) {
        den += __shfl_down(den, off, 64);
        m0  += __shfl_down(m0, off, 64);
        m1  += __shfl_down(m1, off, 64);
    }
    if (lane == 0) {
        float dn = den + EPSF;
        float o0 = m0 / dn + bias2[0];
        float o1 = m1 / dn + bias2[1];
        float mx = fmaxf(o0, o1);
        float lse = mx + logf(expf(o0 - mx) + expf(o1 - mx));
        out[(size_t)n * C + 0] = o0 - lse;
        out[(size_t)n * C + 1] = o1 - lse;
    }
}

extern "C" void kernel_launch(void* const* d_in, const int* in_sizes, int n_in,
                              void* d_out, int out_size, void* d_ws, size_t ws_size,
                              hipStream_t stream) {
    const float* x        = (const float*)d_in[0];
    const int*   ei       = (const int*)d_in[1];
    const float* ea       = (const float*)d_in[2];
    const float* W1       = (const float*)d_in[3];
    const float* att_src1 = (const float*)d_in[4];
    const float* att_dst1 = (const float*)d_in[5];
    const float* W_edge1  = (const float*)d_in[6];
    const float* att_edge1= (const float*)d_in[7];
    const float* bias1    = (const float*)d_in[8];
    const float* W2       = (const float*)d_in[9];
    const float* att_src2 = (const float*)d_in[10];
    const float* att_dst2 = (const float*)d_in[11];
    const float* W_edge2  = (const float*)d_in[12];
    const float* att_edge2= (const float*)d_in[13];
    const float* bias2    = (const float*)d_in[14];

    const int N  = in_sizes[0] / FIN;
    const int E  = in_sizes[1] / 2;
    const int* srcp = ei;
    const int* dstp = ei + E;

    char* wsb = (char*)d_ws;
    size_t off = 0;
    auto alloc = [&](size_t bytes) { void* p = wsb + off; off += (bytes + 255) & ~size_t(255); return p; };
    int*   hist   = (int*)alloc((size_t)N * 4);
    float* sum_ea = (float*)alloc(4);
    size_t zbytes = off;                        // hist + sum_ea must be zeroed
    int*   row    = (int*)alloc((size_t)(N + 1) * 4);
    int*   cursor = (int*)alloc((size_t)N * 4);
    int*   ssrc   = (int*)alloc((size_t)E * 4);
    float* sea    = (float*)alloc((size_t)E * 4);
    float* h1     = (float*)alloc((size_t)N * H * 4);
    float* a_s1   = (float*)alloc((size_t)N * 4);
    float* a_d1   = (float*)alloc((size_t)N * 4);
    float* h2     = (float*)alloc((size_t)N * C * 4);
    float* a_s2   = (float*)alloc((size_t)N * 4);
    float* a_d2   = (float*)alloc((size_t)N * 4);
    float* scal   = (float*)alloc(3 * 4);

    hipMemsetAsync(d_ws, 0, zbytes, stream);

    ea_sum_kernel<<<1024, 256, 0, stream>>>(ea, E, sum_ea);
    scalars_kernel<<<1, 64, 0, stream>>>(sum_ea, E, W_edge1, att_edge1, W_edge2, att_edge2, scal);
    hist_kernel<<<(E + 255) / 256, 256, 0, stream>>>(dstp, E, hist);
    scan_kernel<<<1, 1024, 0, stream>>>(hist, row, cursor, N);
    scatter_kernel<<<(E + 255) / 256, 256, 0, stream>>>(srcp, dstp, ea, E, cursor, ssrc, sea);
    gemm1_kernel<<<(N + NPB - 1) / NPB, 512, 0, stream>>>(x, W1, att_src1, att_dst1, h1, a_s1, a_d1, N);
    agg1_kernel<<<(N + 3) / 4, 256, 0, stream>>>(row, ssrc, sea, scal, a_s1, a_d1, h1,
                                                 bias1, W2, att_src2, att_dst2,
                                                 h2, a_s2, a_d2, N);
    agg2_kernel<<<(N + 3) / 4, 256, 0, stream>>>(row, ssrc, sea, scal, a_s2, a_d2, h2, bias2,
                                                 (float*)d_out, N);
}

// Round 3
// 540.546 us; speedup vs baseline: 1.7651x; 1.4198x over previous
//
#include <hip/hip_runtime.h>
#include <math.h>

#define NEG_SLOPE 0.2f
#define EPSF 1e-16f

constexpr int FIN = 128;
constexpr int H   = 64;
constexpr int C   = 2;

// ---------- scalar precompute ----------
__global__ void ea_sum_kernel(const float* __restrict__ ea, int E, float* __restrict__ out) {
    float acc = 0.f;
    for (int i = blockIdx.x * blockDim.x + threadIdx.x; i < E; i += gridDim.x * blockDim.x)
        acc += ea[i];
    for (int off = 32; off; off >>= 1) acc += __shfl_down(acc, off, 64);
    __shared__ float wsum[4];
    int lane = threadIdx.x & 63, wv = threadIdx.x >> 6;
    if (lane == 0) wsum[wv] = acc;
    __syncthreads();
    if (threadIdx.x == 0) atomicAdd(out, wsum[0] + wsum[1] + wsum[2] + wsum[3]);
}

__global__ void scalars_kernel(const float* __restrict__ sum_ea, int E,
                               const float* __restrict__ W_edge1, const float* __restrict__ att_edge1,
                               const float* __restrict__ W_edge2, const float* __restrict__ att_edge2,
                               float* __restrict__ out3) {
    if (threadIdx.x == 0) {
        float m = *sum_ea / (float)E;
        float c1 = 0.f;
        for (int i = 0; i < H; i++) c1 += W_edge1[i] * att_edge1[i];
        float c2 = 0.f;
        for (int i = 0; i < C; i++) c2 += W_edge2[i] * att_edge2[i];
        out3[0] = m; out3[1] = c1; out3[2] = c2;
    }
}

// ---------- CSR build: histogram of dst ----------
__global__ void hist_kernel(const int* __restrict__ dst, int E, int* __restrict__ hist) {
    int e = blockIdx.x * blockDim.x + threadIdx.x;
    if (e < E) atomicAdd(&hist[dst[e]], 1);
}

// ---------- scan stage 1: per-block (1024 elems) sums ----------
__global__ __launch_bounds__(256) void bsum_kernel(const int* __restrict__ hist, int N,
                                                   int* __restrict__ bsum) {
    int base = blockIdx.x * 1024;
    int t = threadIdx.x;
    int s = 0;
    #pragma unroll
    for (int j = 0; j < 4; j++) {
        int i = base + t * 4 + j;
        if (i < N) s += hist[i];
    }
    __shared__ int red[256];
    red[t] = s;
    __syncthreads();
    for (int off = 128; off; off >>= 1) {
        if (t < off) red[t] += red[t + off];
        __syncthreads();
    }
    if (t == 0) bsum[blockIdx.x] = red[0];
}

// ---------- scan stage 2: scan the block sums (B <= 1024) ----------
__global__ __launch_bounds__(1024) void bscan_kernel(const int* __restrict__ bsum, int B,
                                                     int* __restrict__ boff, int* __restrict__ rowN) {
    __shared__ int sh[1024];
    int t = threadIdx.x;
    int v = (t < B) ? bsum[t] : 0;
    sh[t] = v;
    __syncthreads();
    for (int off = 1; off < 1024; off <<= 1) {
        int u = (t >= off) ? sh[t - off] : 0;
        __syncthreads();
        sh[t] += u;
        __syncthreads();
    }
    if (t < B) boff[t] = sh[t] - v;          // exclusive
    if (t == 1023) *rowN = sh[1023];         // grand total
}

// ---------- scan stage 3: per-block exclusive scan + offset -> row, cursor ----------
__global__ __launch_bounds__(256) void bexc_kernel(const int* __restrict__ hist, int N,
                                                   const int* __restrict__ boff,
                                                   int* __restrict__ row, int* __restrict__ cursor) {
    int base = blockIdx.x * 1024;
    int t = threadIdx.x;
    int v[4]; int s = 0;
    #pragma unroll
    for (int j = 0; j < 4; j++) {
        int i = base + t * 4 + j;
        v[j] = (i < N) ? hist[i] : 0;
        s += v[j];
    }
    __shared__ int sh[256];
    sh[t] = s;
    __syncthreads();
    for (int off = 1; off < 256; off <<= 1) {
        int u = (t >= off) ? sh[t - off] : 0;
        __syncthreads();
        sh[t] += u;
        __syncthreads();
    }
    int run = sh[t] - s + boff[blockIdx.x];  // exclusive prefix for this thread
    #pragma unroll
    for (int j = 0; j < 4; j++) {
        int i = base + t * 4 + j;
        if (i < N) { row[i] = run; cursor[i] = run; run += v[j]; }
    }
}

// ---------- CSR build: scatter edges (packed int2 {src, ea_bits}) ----------
__global__ void scatter_kernel(const int* __restrict__ src, const int* __restrict__ dst,
                               const float* __restrict__ ea, int E,
                               int* __restrict__ cursor, int2* __restrict__ sedge) {
    int e = blockIdx.x * blockDim.x + threadIdx.x;
    if (e >= E) return;
    int d = dst[e];
    int pos = atomicAdd(&cursor[d], 1);
    sedge[pos] = make_int2(src[e], __float_as_int(ea[e]));
}

// ---------- layer 1 GEMM + per-node logits ----------
#define NPB 8
__global__ __launch_bounds__(512) void gemm1_kernel(
        const float* __restrict__ x, const float* __restrict__ W1,
        const float* __restrict__ att_src, const float* __restrict__ att_dst,
        float* __restrict__ h1, float* __restrict__ a_s, float* __restrict__ a_d, int N) {
    __shared__ float sW[FIN * H];      // 32 KB
    __shared__ float sx[NPB][FIN];     // 4 KB
    int tid = threadIdx.x;
    for (int i = tid; i < FIN * H; i += 512) sW[i] = W1[i];
    int node0 = blockIdx.x * NPB;
    for (int i = tid; i < NPB * FIN; i += 512) {
        int n = node0 + i / FIN;
        sx[i / FIN][i % FIN] = (n < N) ? x[(size_t)n * FIN + (i % FIN)] : 0.f;
    }
    __syncthreads();
    int wv = tid >> 6;
    int lane = tid & 63;
    int n = node0 + wv;
    if (n >= N) return;
    const float* xr = sx[wv];
    float acc = 0.f;
    #pragma unroll 8
    for (int k = 0; k < FIN; k++) acc += xr[k] * sW[k * H + lane];
    h1[(size_t)n * H + lane] = acc;
    float ps = acc * att_src[lane];
    float pd = acc * att_dst[lane];
    for (int off = 32; off; off >>= 1) {
        ps += __shfl_down(ps, off, 64);
        pd += __shfl_down(pd, off, 64);
    }
    if (lane == 0) { a_s[n] = ps; a_d[n] = pd; }
}

// ---------- layer 1 aggregation (wave per dst node) + node1 + gemm2 fused ----------
__global__ __launch_bounds__(256) void agg1_kernel(
        const int* __restrict__ row, const int2* __restrict__ sedge,
        const float* __restrict__ scal,
        const float* __restrict__ a_s, const float* __restrict__ a_d,
        const float* __restrict__ h1,
        const float* __restrict__ bias1, const float* __restrict__ W2,
        const float* __restrict__ att_src2, const float* __restrict__ att_dst2,
        float* __restrict__ h2, float* __restrict__ a_s2, float* __restrict__ a_d2,
        int N) {
    int n = (blockIdx.x << 2) + (threadIdx.x >> 6);   // dst node
    int lane = threadIdx.x & 63;
    if (n >= N) return;
    float c1 = scal[1];
    float ad = a_d[n];
    int beg = row[n], end = row[n + 1];
    float den = 0.f, acc = 0.f;
    int i = beg;
    for (; i + 2 <= end; i += 2) {
        int2 e0v = sedge[i], e1v = sedge[i + 1];
        int s0 = e0v.x, s1 = e1v.x;
        float ae0 = __int_as_float(e0v.y) * c1, ae1 = __int_as_float(e1v.y) * c1;
        float as0 = a_s[s0], as1 = a_s[s1];
        float h0 = h1[(size_t)s0 * H + lane];
        float hv1 = h1[(size_t)s1 * H + lane];
        float lg0 = as0 + ad + ae0; lg0 = lg0 > 0.f ? lg0 : NEG_SLOPE * lg0;
        float lg1 = as1 + ad + ae1; lg1 = lg1 > 0.f ? lg1 : NEG_SLOPE * lg1;
        float e0 = __expf(lg0), e1 = __expf(lg1);
        den += e0 + e1;
        acc += e0 * h0 + e1 * hv1;
    }
    for (; i < end; i++) {
        int2 ev = sedge[i];
        int s = ev.x;
        float lg = a_s[s] + ad + __int_as_float(ev.y) * c1;
        lg = lg > 0.f ? lg : NEG_SLOPE * lg;
        float ex = __expf(lg);
        den += ex;
        acc += ex * h1[(size_t)s * H + lane];
    }
    // self loop (src = dst = n, edge_attr = mean)
    {
        float lg = a_s[n] + ad + scal[0] * c1;
        lg = lg > 0.f ? lg : NEG_SLOPE * lg;
        float ex = __expf(lg);
        den += ex;
        acc += ex * h1[(size_t)n * H + lane];
    }
    float hr = acc / (den + EPSF) + bias1[lane];
    hr = fmaxf(hr, 0.f);
    // fused gemm2: h2 = hr @ W2  (64 -> 2)
    float p0 = hr * W2[lane * C + 0];
    float p1 = hr * W2[lane * C + 1];
    for (int off = 32; off; off >>= 1) {
        p0 += __shfl_down(p0, off, 64);
        p1 += __shfl_down(p1, off, 64);
    }
    if (lane == 0) {
        h2[(size_t)n * C + 0] = p0;
        h2[(size_t)n * C + 1] = p1;
        a_s2[n] = p0 * att_src2[0] + p1 * att_src2[1];
        a_d2[n] = p0 * att_dst2[0] + p1 * att_dst2[1];
    }
}

// ---------- layer 2 aggregation (wave per dst node, lanes over edges) + log_softmax ----------
__global__ __launch_bounds__(256) void agg2_kernel(
        const int* __restrict__ row, const int2* __restrict__ sedge,
        const float* __restrict__ scal,
        const float* __restrict__ a_s2, const float* __restrict__ a_d2,
        const float* __restrict__ h2, const float* __restrict__ bias2,
        float* __restrict__ out, int N) {
    int n = (blockIdx.x << 2) + (threadIdx.x >> 6);
    int lane = threadIdx.x & 63;
    if (n >= N) return;
    float c2 = scal[2];
    float ad = a_d2[n];
    int beg = row[n], end = row[n + 1];
    float den = 0.f, m0 = 0.f, m1 = 0.f;
    for (int i = beg + lane; i < end; i += 64) {
        int2 ev = sedge[i];
        int s = ev.x;
        float lg = a_s2[s] + ad + __int_as_float(ev.y) * c2;
        lg = lg > 0.f ? lg : NEG_SLOPE * lg;
        float ex = __expf(lg);
        den += ex;
        m0 += ex * h2[(size_t)s * C + 0];
        m1 += ex * h2[(size_t)s * C + 1];
    }
    if (lane == 0) {   // self loop
        float lg = a_s2[n] + ad + scal[0] * c2;
        lg = lg > 0.f ? lg : NEG_SLOPE * lg;
        float ex = __expf(lg);
        den += ex;
        m0 += ex * h2[(size_t)n * C + 0];
        m1 += ex * h2[(size_t)n * C + 1];
    }
    for (int off = 32; off; off >>= 1) {
        den += __shfl_down(den, off, 64);
        m0  += __shfl_down(m0, off, 64);
        m1  += __shfl_down(m1, off, 64);
    }
    if (lane == 0) {
        float dn = den + EPSF;
        float o0 = m0 / dn + bias2[0];
        float o1 = m1 / dn + bias2[1];
        float mx = fmaxf(o0, o1);
        float lse = mx + logf(expf(o0 - mx) + expf(o1 - mx));
        out[(size_t)n * C + 0] = o0 - lse;
        out[(size_t)n * C + 1] = o1 - lse;
    }
}

extern "C" void kernel_launch(void* const* d_in, const int* in_sizes, int n_in,
                              void* d_out, int out_size, void* d_ws, size_t ws_size,
                              hipStream_t stream) {
    const float* x        = (const float*)d_in[0];
    const int*   ei       = (const int*)d_in[1];
    const float* ea       = (const float*)d_in[2];
    const float* W1       = (const float*)d_in[3];
    const float* att_src1 = (const float*)d_in[4];
    const float* att_dst1 = (const float*)d_in[5];
    const float* W_edge1  = (const float*)d_in[6];
    const float* att_edge1= (const float*)d_in[7];
    const float* bias1    = (const float*)d_in[8];
    const float* W2       = (const float*)d_in[9];
    const float* att_src2 = (const float*)d_in[10];
    const float* att_dst2 = (const float*)d_in[11];
    const float* W_edge2  = (const float*)d_in[12];
    const float* att_edge2= (const float*)d_in[13];
    const float* bias2    = (const float*)d_in[14];

    const int N  = in_sizes[0] / FIN;
    const int E  = in_sizes[1] / 2;
    const int* srcp = ei;
    const int* dstp = ei + E;
    const int NB = (N + 1023) / 1024;    // scan blocks (98 for N=100k)

    char* wsb = (char*)d_ws;
    size_t off = 0;
    auto alloc = [&](size_t bytes) { void* p = wsb + off; off += (bytes + 255) & ~size_t(255); return p; };
    int*   hist   = (int*)alloc((size_t)N * 4);
    float* sum_ea = (float*)alloc(4);
    size_t zbytes = off;                        // hist + sum_ea must be zeroed
    int*   row    = (int*)alloc((size_t)(N + 1) * 4);
    int*   cursor = (int*)alloc((size_t)N * 4);
    int*   bsum   = (int*)alloc((size_t)NB * 4);
    int*   boff   = (int*)alloc((size_t)NB * 4);
    int2*  sedge  = (int2*)alloc((size_t)E * 8);
    float* h1     = (float*)alloc((size_t)N * H * 4);
    float* a_s1   = (float*)alloc((size_t)N * 4);
    float* a_d1   = (float*)alloc((size_t)N * 4);
    float* h2     = (float*)alloc((size_t)N * C * 4);
    float* a_s2   = (float*)alloc((size_t)N * 4);
    float* a_d2   = (float*)alloc((size_t)N * 4);
    float* scal   = (float*)alloc(3 * 4);

    hipMemsetAsync(d_ws, 0, zbytes, stream);

    ea_sum_kernel<<<1024, 256, 0, stream>>>(ea, E, sum_ea);
    scalars_kernel<<<1, 64, 0, stream>>>(sum_ea, E, W_edge1, att_edge1, W_edge2, att_edge2, scal);
    hist_kernel<<<(E + 255) / 256, 256, 0, stream>>>(dstp, E, hist);
    bsum_kernel<<<NB, 256, 0, stream>>>(hist, N, bsum);
    bscan_kernel<<<1, 1024, 0, stream>>>(bsum, NB, boff, row + N);
    bexc_kernel<<<NB, 256, 0, stream>>>(hist, N, boff, row, cursor);
    scatter_kernel<<<(E + 255) / 256, 256, 0, stream>>>(srcp, dstp, ea, E, cursor, sedge);
    gemm1_kernel<<<(N + NPB - 1) / NPB, 512, 0, stream>>>(x, W1, att_src1, att_dst1, h1, a_s1, a_d1, N);
    agg1_kernel<<<(N + 3) / 4, 256, 0, stream>>>(row, sedge, scal, a_s1, a_d1, h1,
                                                 bias1, W2, att_src2, att_dst2,
                                                 h2, a_s2, a_d2, N);
    agg2_kernel<<<(N + 3) / 4, 256, 0, stream>>>(row, sedge, scal, a_s2, a_d2, h2, bias2,
                                                 (float*)d_out, N);
}

// Round 4
// 442.020 us; speedup vs baseline: 2.1585x; 1.2229x over previous
//
#include <hip/hip_runtime.h>
#include <math.h>

#define NEG_SLOPE 0.2f
#define EPSF 1e-16f

constexpr int FIN = 128;
constexpr int H   = 64;
constexpr int C   = 2;
constexpr int BSHIFT = 10;              // nodes per bucket = 1024
constexpr int NBUCK_MAX = 1024;         // supports N <= 1M
constexpr int CHUNK = 4096;             // edges per stage block

// ---------- scalar precompute ----------
__global__ void ea_sum_kernel(const float* __restrict__ ea, int E, float* __restrict__ out) {
    float acc = 0.f;
    for (int i = blockIdx.x * blockDim.x + threadIdx.x; i < E; i += gridDim.x * blockDim.x)
        acc += ea[i];
    for (int off = 32; off; off >>= 1) acc += __shfl_down(acc, off, 64);
    __shared__ float wsum[4];
    int lane = threadIdx.x & 63, wv = threadIdx.x >> 6;
    if (lane == 0) wsum[wv] = acc;
    __syncthreads();
    if (threadIdx.x == 0) atomicAdd(out, wsum[0] + wsum[1] + wsum[2] + wsum[3]);
}

__global__ void scalars_kernel(const float* __restrict__ sum_ea, int E,
                               const float* __restrict__ W_edge1, const float* __restrict__ att_edge1,
                               const float* __restrict__ W_edge2, const float* __restrict__ att_edge2,
                               float* __restrict__ out3) {
    if (threadIdx.x == 0) {
        float m = *sum_ea / (float)E;
        float c1 = 0.f;
        for (int i = 0; i < H; i++) c1 += W_edge1[i] * att_edge1[i];
        float c2 = 0.f;
        for (int i = 0; i < C; i++) c2 += W_edge2[i] * att_edge2[i];
        out3[0] = m; out3[1] = c1; out3[2] = c2;
    }
}

// ---------- P0: bucket counts (LDS-aggregated) ----------
__global__ __launch_bounds__(256) void bcount_kernel(const int* __restrict__ dst, int E,
                                                     int* __restrict__ bcount, int NBUCK) {
    __shared__ int lh[NBUCK_MAX];
    for (int i = threadIdx.x; i < NBUCK_MAX; i += 256) lh[i] = 0;
    __syncthreads();
    for (int e = blockIdx.x * 256 + threadIdx.x; e < E; e += gridDim.x * 256)
        atomicAdd(&lh[dst[e] >> BSHIFT], 1);
    __syncthreads();
    for (int i = threadIdx.x; i < NBUCK; i += 256)
        if (lh[i]) atomicAdd(&bcount[i], lh[i]);
}

// ---------- P1: scan bucket counts -> bbase, bcursor ----------
__global__ __launch_bounds__(1024) void bscan_kernel(const int* __restrict__ bcount, int NBUCK, int E,
                                                     int* __restrict__ bbase, int* __restrict__ bcursor,
                                                     int* __restrict__ rowN) {
    __shared__ int sh[1024];
    int t = threadIdx.x;
    int v = (t < NBUCK) ? bcount[t] : 0;
    sh[t] = v;
    __syncthreads();
    for (int off = 1; off < 1024; off <<= 1) {
        int u = (t >= off) ? sh[t - off] : 0;
        __syncthreads();
        sh[t] += u;
        __syncthreads();
    }
    if (t < NBUCK) { bbase[t] = sh[t] - v; bcursor[t] = sh[t] - v; }
    if (t == 0) { bbase[NBUCK] = E; *rowN = E; }
}

// ---------- P2: stage edges into bucket-major order (coalesced runs) ----------
__global__ __launch_bounds__(256) void stage_kernel(
        const int* __restrict__ src, const int* __restrict__ dst, const float* __restrict__ ea,
        int E, int* __restrict__ bcursor, int2* __restrict__ staging, int NBUCK) {
    __shared__ int   cur[NBUCK_MAX];
    __shared__ int   gofs[NBUCK_MAX];
    __shared__ int2  sbuf[CHUNK];
    __shared__ short sbkt[CHUNK];
    __shared__ int   red[256];
    int t = threadIdx.x;
    int base = blockIdx.x * CHUNK;
    int cnt = min(CHUNK, E - base);
    for (int i = t; i < NBUCK_MAX; i += 256) cur[i] = 0;
    __syncthreads();
    // pass A: histogram over this chunk
    for (int i = t; i < cnt; i += 256)
        atomicAdd(&cur[dst[base + i] >> BSHIFT], 1);
    __syncthreads();
    // scan: 4 entries per thread
    int i0 = t * 4;
    int v0 = cur[i0], v1 = cur[i0 + 1], v2 = cur[i0 + 2], v3 = cur[i0 + 3];
    int s = v0 + v1 + v2 + v3;
    red[t] = s;
    __syncthreads();
    for (int off = 1; off < 256; off <<= 1) {
        int u = (t >= off) ? red[t - off] : 0;
        __syncthreads();
        red[t] += u;
        __syncthreads();
    }
    int run = red[t] - s;                 // exclusive prefix (within chunk)
    __syncthreads();
    // write cursor starts + reserve global space per bucket
    int p = run;
    if (v0) gofs[i0]     = atomicAdd(&bcursor[i0],     v0) - p;
    cur[i0] = p; p += v0;
    if (v1) gofs[i0 + 1] = atomicAdd(&bcursor[i0 + 1], v1) - p;
    cur[i0 + 1] = p; p += v1;
    if (v2) gofs[i0 + 2] = atomicAdd(&bcursor[i0 + 2], v2) - p;
    cur[i0 + 2] = p; p += v2;
    if (v3) gofs[i0 + 3] = atomicAdd(&bcursor[i0 + 3], v3) - p;
    cur[i0 + 3] = p; p += v3;
    __syncthreads();
    // pass B: reorder into LDS, record bucket per slot
    for (int i = t; i < cnt; i += 256) {
        int e = base + i;
        int d = dst[e];
        int b = d >> BSHIFT;
        int slot = atomicAdd(&cur[b], 1);
        sbuf[slot] = make_int2(src[e] | ((d & ((1 << BSHIFT) - 1)) << 20), __float_as_int(ea[e]));
        sbkt[slot] = (short)b;
    }
    __syncthreads();
    // coalesced write-out: consecutive slots -> consecutive global addresses per run
    for (int j = t; j < cnt; j += 256)
        staging[gofs[sbkt[j]] + j] = sbuf[j];
}

// ---------- P3: per-bucket finalize: per-node CSR rows + in-window scatter ----------
__global__ __launch_bounds__(256) void bfin_kernel(
        const int2* __restrict__ staging, const int* __restrict__ bbase,
        int* __restrict__ row, int2* __restrict__ sedge, int N) {
    __shared__ int nh[NBUCK_MAX];   // per-node counts -> cursors (1024 nodes/bucket)
    __shared__ int red[256];
    int b = blockIdx.x, t = threadIdx.x;
    int beg = bbase[b], end = bbase[b + 1];
    int node0 = b << BSHIFT;
    for (int i = t; i < NBUCK_MAX; i += 256) nh[i] = 0;
    __syncthreads();
    for (int i = beg + t; i < end; i += 256)
        atomicAdd(&nh[(unsigned)staging[i].x >> 20], 1);
    __syncthreads();
    int i0 = t * 4;
    int v0 = nh[i0], v1 = nh[i0 + 1], v2 = nh[i0 + 2], v3 = nh[i0 + 3];
    int s = v0 + v1 + v2 + v3;
    red[t] = s;
    __syncthreads();
    for (int off = 1; off < 256; off <<= 1) {
        int u = (t >= off) ? red[t - off] : 0;
        __syncthreads();
        red[t] += u;
        __syncthreads();
    }
    int run = red[t] - s + beg;           // absolute CSR position
    __syncthreads();
    int p = run;
    #pragma unroll
    for (int j = 0; j < 4; j++) {
        int idx = i0 + j;
        int v = (j == 0) ? v0 : (j == 1) ? v1 : (j == 2) ? v2 : v3;
        int node = node0 + idx;
        if (node < N) row[node] = p;
        nh[idx] = p;                      // cursor start
        p += v;
    }
    __syncthreads();
    for (int i = beg + t; i < end; i += 256) {
        int2 r = staging[i];
        int dlow = (unsigned)r.x >> 20;
        int pos = atomicAdd(&nh[dlow], 1);
        sedge[pos] = make_int2(r.x & 0xFFFFF, r.y);
    }
}

// ---------- layer 1 GEMM + per-node logits ----------
#define NPB 8
__global__ __launch_bounds__(512) void gemm1_kernel(
        const float* __restrict__ x, const float* __restrict__ W1,
        const float* __restrict__ att_src, const float* __restrict__ att_dst,
        float* __restrict__ h1, float* __restrict__ a_s, float* __restrict__ a_d, int N) {
    __shared__ float sW[FIN * H];      // 32 KB
    __shared__ float sx[NPB][FIN];     // 4 KB
    int tid = threadIdx.x;
    for (int i = tid; i < FIN * H; i += 512) sW[i] = W1[i];
    int node0 = blockIdx.x * NPB;
    for (int i = tid; i < NPB * FIN; i += 512) {
        int n = node0 + i / FIN;
        sx[i / FIN][i % FIN] = (n < N) ? x[(size_t)n * FIN + (i % FIN)] : 0.f;
    }
    __syncthreads();
    int wv = tid >> 6;
    int lane = tid & 63;
    int n = node0 + wv;
    if (n >= N) return;
    const float* xr = sx[wv];
    float acc = 0.f;
    #pragma unroll 8
    for (int k = 0; k < FIN; k++) acc += xr[k] * sW[k * H + lane];
    h1[(size_t)n * H + lane] = acc;
    float ps = acc * att_src[lane];
    float pd = acc * att_dst[lane];
    for (int off = 32; off; off >>= 1) {
        ps += __shfl_down(ps, off, 64);
        pd += __shfl_down(pd, off, 64);
    }
    if (lane == 0) { a_s[n] = ps; a_d[n] = pd; }
}

// ---------- layer 1 aggregation (wave per dst node) + node1 + gemm2 fused ----------
__global__ __launch_bounds__(256) void agg1_kernel(
        const int* __restrict__ row, const int2* __restrict__ sedge,
        const float* __restrict__ scal,
        const float* __restrict__ a_s, const float* __restrict__ a_d,
        const float* __restrict__ h1,
        const float* __restrict__ bias1, const float* __restrict__ W2,
        const float* __restrict__ att_src2, const float* __restrict__ att_dst2,
        float* __restrict__ h2, float* __restrict__ a_s2, float* __restrict__ a_d2,
        int N) {
    int n = (blockIdx.x << 2) + (threadIdx.x >> 6);   // dst node
    int lane = threadIdx.x & 63;
    if (n >= N) return;
    float c1 = scal[1];
    float ad = a_d[n];
    int beg = row[n], end = row[n + 1];
    float den = 0.f, acc = 0.f;
    int i = beg;
    for (; i + 4 <= end; i += 4) {
        int2 e0v = sedge[i], e1v = sedge[i + 1], e2v = sedge[i + 2], e3v = sedge[i + 3];
        int s0 = e0v.x, s1 = e1v.x, s2 = e2v.x, s3 = e3v.x;
        float h0 = h1[(size_t)s0 * H + lane];
        float hA = h1[(size_t)s1 * H + lane];
        float hB = h1[(size_t)s2 * H + lane];
        float hC = h1[(size_t)s3 * H + lane];
        float as0 = a_s[s0], as1 = a_s[s1], as2 = a_s[s2], as3 = a_s[s3];
        float lg0 = as0 + ad + __int_as_float(e0v.y) * c1; lg0 = lg0 > 0.f ? lg0 : NEG_SLOPE * lg0;
        float lg1 = as1 + ad + __int_as_float(e1v.y) * c1; lg1 = lg1 > 0.f ? lg1 : NEG_SLOPE * lg1;
        float lg2 = as2 + ad + __int_as_float(e2v.y) * c1; lg2 = lg2 > 0.f ? lg2 : NEG_SLOPE * lg2;
        float lg3 = as3 + ad + __int_as_float(e3v.y) * c1; lg3 = lg3 > 0.f ? lg3 : NEG_SLOPE * lg3;
        float e0 = __expf(lg0), e1 = __expf(lg1), e2 = __expf(lg2), e3 = __expf(lg3);
        den += (e0 + e1) + (e2 + e3);
        acc += e0 * h0 + e1 * hA + e2 * hB + e3 * hC;
    }
    for (; i < end; i++) {
        int2 ev = sedge[i];
        int s = ev.x;
        float lg = a_s[s] + ad + __int_as_float(ev.y) * c1;
        lg = lg > 0.f ? lg : NEG_SLOPE * lg;
        float ex = __expf(lg);
        den += ex;
        acc += ex * h1[(size_t)s * H + lane];
    }
    // self loop (src = dst = n, edge_attr = mean)
    {
        float lg = a_s[n] + ad + scal[0] * c1;
        lg = lg > 0.f ? lg : NEG_SLOPE * lg;
        float ex = __expf(lg);
        den += ex;
        acc += ex * h1[(size_t)n * H + lane];
    }
    float hr = acc / (den + EPSF) + bias1[lane];
    hr = fmaxf(hr, 0.f);
    // fused gemm2: h2 = hr @ W2  (64 -> 2)
    float p0 = hr * W2[lane * C + 0];
    float p1 = hr * W2[lane * C + 1];
    for (int off = 32; off; off >>= 1) {
        p0 += __shfl_down(p0, off, 64);
        p1 += __shfl_down(p1, off, 64);
    }
    if (lane == 0) {
        h2[(size_t)n * C + 0] = p0;
        h2[(size_t)n * C + 1] = p1;
        a_s2[n] = p0 * att_src2[0] + p1 * att_src2[1];
        a_d2[n] = p0 * att_dst2[0] + p1 * att_dst2[1];
    }
}

// ---------- layer 2 aggregation (wave per dst node, lanes over edges) + log_softmax ----------
__global__ __launch_bounds__(256) void agg2_kernel(
        const int* __restrict__ row, const int2* __restrict__ sedge,
        const float* __restrict__ scal,
        const float* __restrict__ a_s2, const float* __restrict__ a_d2,
        const float* __restrict__ h2, const float* __restrict__ bias2,
        float* __restrict__ out, int N) {
    int n = (blockIdx.x << 2) + (threadIdx.x >> 6);
    int lane = threadIdx.x & 63;
    if (n >= N) return;
    float c2 = scal[2];
    float ad = a_d2[n];
    int beg = row[n], end = row[n + 1];
    float den = 0.f, m0 = 0.f, m1 = 0.f;
    for (int i = beg + lane; i < end; i += 64) {
        int2 ev = sedge[i];
        int s = ev.x;
        float lg = a_s2[s] + ad + __int_as_float(ev.y) * c2;
        lg = lg > 0.f ? lg : NEG_SLOPE * lg;
        float ex = __expf(lg);
        den += ex;
        m0 += ex * h2[(size_t)s * C + 0];
        m1 += ex * h2[(size_t)s * C + 1];
    }
    if (lane == 0) {   // self loop
        float lg = a_s2[n] + ad + scal[0] * c2;
        lg = lg > 0.f ? lg : NEG_SLOPE * lg;
        float ex = __expf(lg);
        den += ex;
        m0 += ex * h2[(size_t)n * C + 0];
        m1 += ex * h2[(size_t)n * C + 1];
    }
    for (int off = 32; off; off >>= 1) {
        den += __shfl_down(den, off, 64);
        m0  += __shfl_down(m0, off, 64);
        m1  += __shfl_down(m1, off, 64);
    }
    if (lane == 0) {
        float dn = den + EPSF;
        float o0 = m0 / dn + bias2[0];
        float o1 = m1 / dn + bias2[1];
        float mx = fmaxf(o0, o1);
        float lse = mx + logf(expf(o0 - mx) + expf(o1 - mx));
        out[(size_t)n * C + 0] = o0 - lse;
        out[(size_t)n * C + 1] = o1 - lse;
    }
}

extern "C" void kernel_launch(void* const* d_in, const int* in_sizes, int n_in,
                              void* d_out, int out_size, void* d_ws, size_t ws_size,
                              hipStream_t stream) {
    const float* x        = (const float*)d_in[0];
    const int*   ei       = (const int*)d_in[1];
    const float* ea       = (const float*)d_in[2];
    const float* W1       = (const float*)d_in[3];
    const float* att_src1 = (const float*)d_in[4];
    const float* att_dst1 = (const float*)d_in[5];
    const float* W_edge1  = (const float*)d_in[6];
    const float* att_edge1= (const float*)d_in[7];
    const float* bias1    = (const float*)d_in[8];
    const float* W2       = (const float*)d_in[9];
    const float* att_src2 = (const float*)d_in[10];
    const float* att_dst2 = (const float*)d_in[11];
    const float* W_edge2  = (const float*)d_in[12];
    const float* att_edge2= (const float*)d_in[13];
    const float* bias2    = (const float*)d_in[14];

    const int N  = in_sizes[0] / FIN;
    const int E  = in_sizes[1] / 2;
    const int* srcp = ei;
    const int* dstp = ei + E;
    const int NBUCK = (N + (1 << BSHIFT) - 1) >> BSHIFT;   // 98 for N=100k

    char* wsb = (char*)d_ws;
    size_t off = 0;
    auto alloc = [&](size_t bytes) { void* p = wsb + off; off += (bytes + 255) & ~size_t(255); return p; };
    int*   bcount = (int*)alloc((size_t)NBUCK_MAX * 4);
    float* sum_ea = (float*)alloc(4);
    size_t zbytes = off;                        // bcount + sum_ea must be zeroed
    int*   bbase  = (int*)alloc((size_t)(NBUCK_MAX + 1) * 4);
    int*   bcursor= (int*)alloc((size_t)NBUCK_MAX * 4);
    int*   row    = (int*)alloc((size_t)(N + 1) * 4);
    int2*  sedge  = (int2*)alloc((size_t)E * 8);
    float* h1     = (float*)alloc((size_t)N * H * 4);
    int2*  staging= (int2*)h1;                  // staging (E*8 B) dead before gemm1 writes h1 (N*H*4 B >= E*8)
    float* a_s1   = (float*)alloc((size_t)N * 4);
    float* a_d1   = (float*)alloc((size_t)N * 4);
    float* h2     = (float*)alloc((size_t)N * C * 4);
    float* a_s2   = (float*)alloc((size_t)N * 4);
    float* a_d2   = (float*)alloc((size_t)N * 4);
    float* scal   = (float*)alloc(3 * 4);

    hipMemsetAsync(d_ws, 0, zbytes, stream);

    ea_sum_kernel<<<1024, 256, 0, stream>>>(ea, E, sum_ea);
    scalars_kernel<<<1, 64, 0, stream>>>(sum_ea, E, W_edge1, att_edge1, W_edge2, att_edge2, scal);
    bcount_kernel<<<256, 256, 0, stream>>>(dstp, E, bcount, NBUCK);
    bscan_kernel<<<1, 1024, 0, stream>>>(bcount, NBUCK, E, bbase, bcursor, row + N);
    stage_kernel<<<(E + CHUNK - 1) / CHUNK, 256, 0, stream>>>(srcp, dstp, ea, E, bcursor, staging, NBUCK);
    bfin_kernel<<<NBUCK, 256, 0, stream>>>(staging, bbase, row, sedge, N);
    gemm1_kernel<<<(N + NPB - 1) / NPB, 512, 0, stream>>>(x, W1, att_src1, att_dst1, h1, a_s1, a_d1, N);
    agg1_kernel<<<(N + 3) / 4, 256, 0, stream>>>(row, sedge, scal, a_s1, a_d1, h1,
                                                 bias1, W2, att_src2, att_dst2,
                                                 h2, a_s2, a_d2, N);
    agg2_kernel<<<(N + 3) / 4, 256, 0, stream>>>(row, sedge, scal, a_s2, a_d2, h2, bias2,
                                                 (float*)d_out, N);
}

// Round 5
// 385.966 us; speedup vs baseline: 2.4720x; 1.1452x over previous
//
#include <hip/hip_runtime.h>
#include <math.h>

#define NEG_SLOPE 0.2f
#define EPSF 1e-16f

constexpr int FIN = 128;
constexpr int H   = 64;
constexpr int C   = 2;
constexpr int BSHIFT = 10;              // nodes per bucket = 1024
constexpr int NBUCK_MAX = 1024;         // supports N <= 1M
constexpr int CHUNK = 4096;             // edges per stage block

typedef short v8s __attribute__((ext_vector_type(8)));
typedef float v4f __attribute__((ext_vector_type(4)));
typedef unsigned short u16;

// round-to-nearest-even fp32 -> bf16 split (hi + lo captures ~17 mantissa bits)
__device__ inline void split_bf16(float v, u16& hi, u16& lo) {
    unsigned u = __float_as_uint(v);
    unsigned r = (u + 0x7FFFu + ((u >> 16) & 1u)) >> 16;
    hi = (u16)r;
    float hf = __uint_as_float(r << 16);
    float l = v - hf;
    unsigned ul = __float_as_uint(l);
    lo = (u16)((ul + 0x7FFFu + ((ul >> 16) & 1u)) >> 16);
}

// ---------- scalar precompute ----------
__global__ void ea_sum_kernel(const float* __restrict__ ea, int E, float* __restrict__ out) {
    float acc = 0.f;
    for (int i = blockIdx.x * blockDim.x + threadIdx.x; i < E; i += gridDim.x * blockDim.x)
        acc += ea[i];
    for (int off = 32; off; off >>= 1) acc += __shfl_down(acc, off, 64);
    __shared__ float wsum[4];
    int lane = threadIdx.x & 63, wv = threadIdx.x >> 6;
    if (lane == 0) wsum[wv] = acc;
    __syncthreads();
    if (threadIdx.x == 0) atomicAdd(out, wsum[0] + wsum[1] + wsum[2] + wsum[3]);
}

__global__ void scalars_kernel(const float* __restrict__ sum_ea, int E,
                               const float* __restrict__ W_edge1, const float* __restrict__ att_edge1,
                               const float* __restrict__ W_edge2, const float* __restrict__ att_edge2,
                               float* __restrict__ out3) {
    if (threadIdx.x == 0) {
        float m = *sum_ea / (float)E;
        float c1 = 0.f;
        for (int i = 0; i < H; i++) c1 += W_edge1[i] * att_edge1[i];
        float c2 = 0.f;
        for (int i = 0; i < C; i++) c2 += W_edge2[i] * att_edge2[i];
        out3[0] = m; out3[1] = c1; out3[2] = c2;
    }
}

// ---------- W1 prep: transpose to [f][k] + split to bf16 hi/lo ----------
__global__ void wprep_kernel(const float* __restrict__ W1,
                             u16* __restrict__ Wt_hi, u16* __restrict__ Wt_lo) {
    int idx = blockIdx.x * 256 + threadIdx.x;
    if (idx >= FIN * H) return;
    int k = idx >> 6, f = idx & 63;           // W1 is [k][f]
    u16 h, l;
    split_bf16(W1[idx], h, l);
    Wt_hi[f * FIN + k] = h;
    Wt_lo[f * FIN + k] = l;
}

// ---------- P0: bucket counts (LDS-aggregated) ----------
__global__ __launch_bounds__(256) void bcount_kernel(const int* __restrict__ dst, int E,
                                                     int* __restrict__ bcount, int NBUCK) {
    __shared__ int lh[NBUCK_MAX];
    for (int i = threadIdx.x; i < NBUCK_MAX; i += 256) lh[i] = 0;
    __syncthreads();
    for (int e = blockIdx.x * 256 + threadIdx.x; e < E; e += gridDim.x * 256)
        atomicAdd(&lh[dst[e] >> BSHIFT], 1);
    __syncthreads();
    for (int i = threadIdx.x; i < NBUCK; i += 256)
        if (lh[i]) atomicAdd(&bcount[i], lh[i]);
}

// ---------- P1: scan bucket counts -> bbase, bcursor ----------
__global__ __launch_bounds__(1024) void bscan_kernel(const int* __restrict__ bcount, int NBUCK, int E,
                                                     int* __restrict__ bbase, int* __restrict__ bcursor,
                                                     int* __restrict__ rowN) {
    __shared__ int sh[1024];
    int t = threadIdx.x;
    int v = (t < NBUCK) ? bcount[t] : 0;
    sh[t] = v;
    __syncthreads();
    for (int off = 1; off < 1024; off <<= 1) {
        int u = (t >= off) ? sh[t - off] : 0;
        __syncthreads();
        sh[t] += u;
        __syncthreads();
    }
    if (t < NBUCK) { bbase[t] = sh[t] - v; bcursor[t] = sh[t] - v; }
    if (t == 0) { bbase[NBUCK] = E; *rowN = E; }
}

// ---------- P2: stage edges into bucket-major order (coalesced runs) ----------
__global__ __launch_bounds__(256) void stage_kernel(
        const int* __restrict__ src, const int* __restrict__ dst, const float* __restrict__ ea,
        int E, int* __restrict__ bcursor, int2* __restrict__ staging, int NBUCK) {
    __shared__ int   cur[NBUCK_MAX];
    __shared__ int   gofs[NBUCK_MAX];
    __shared__ int2  sbuf[CHUNK];
    __shared__ short sbkt[CHUNK];
    __shared__ int   red[256];
    int t = threadIdx.x;
    int base = blockIdx.x * CHUNK;
    int cnt = min(CHUNK, E - base);
    for (int i = t; i < NBUCK_MAX; i += 256) cur[i] = 0;
    __syncthreads();
    for (int i = t; i < cnt; i += 256)
        atomicAdd(&cur[dst[base + i] >> BSHIFT], 1);
    __syncthreads();
    int i0 = t * 4;
    int v0 = cur[i0], v1 = cur[i0 + 1], v2 = cur[i0 + 2], v3 = cur[i0 + 3];
    int s = v0 + v1 + v2 + v3;
    red[t] = s;
    __syncthreads();
    for (int off = 1; off < 256; off <<= 1) {
        int u = (t >= off) ? red[t - off] : 0;
        __syncthreads();
        red[t] += u;
        __syncthreads();
    }
    int run = red[t] - s;
    __syncthreads();
    int p = run;
    if (v0) gofs[i0]     = atomicAdd(&bcursor[i0],     v0) - p;
    cur[i0] = p; p += v0;
    if (v1) gofs[i0 + 1] = atomicAdd(&bcursor[i0 + 1], v1) - p;
    cur[i0 + 1] = p; p += v1;
    if (v2) gofs[i0 + 2] = atomicAdd(&bcursor[i0 + 2], v2) - p;
    cur[i0 + 2] = p; p += v2;
    if (v3) gofs[i0 + 3] = atomicAdd(&bcursor[i0 + 3], v3) - p;
    cur[i0 + 3] = p; p += v3;
    __syncthreads();
    for (int i = t; i < cnt; i += 256) {
        int e = base + i;
        int d = dst[e];
        int b = d >> BSHIFT;
        int slot = atomicAdd(&cur[b], 1);
        sbuf[slot] = make_int2(src[e] | ((d & ((1 << BSHIFT) - 1)) << 20), __float_as_int(ea[e]));
        sbkt[slot] = (short)b;
    }
    __syncthreads();
    for (int j = t; j < cnt; j += 256)
        staging[gofs[sbkt[j]] + j] = sbuf[j];
}

// ---------- P3: per-bucket finalize: per-node CSR rows + in-window scatter ----------
__global__ __launch_bounds__(256) void bfin_kernel(
        const int2* __restrict__ staging, const int* __restrict__ bbase,
        int* __restrict__ row, int2* __restrict__ sedge, int N) {
    __shared__ int nh[NBUCK_MAX];
    __shared__ int red[256];
    int b = blockIdx.x, t = threadIdx.x;
    int beg = bbase[b], end = bbase[b + 1];
    int node0 = b << BSHIFT;
    for (int i = t; i < NBUCK_MAX; i += 256) nh[i] = 0;
    __syncthreads();
    for (int i = beg + t; i < end; i += 256)
        atomicAdd(&nh[(unsigned)staging[i].x >> 20], 1);
    __syncthreads();
    int i0 = t * 4;
    int v0 = nh[i0], v1 = nh[i0 + 1], v2 = nh[i0 + 2], v3 = nh[i0 + 3];
    int s = v0 + v1 + v2 + v3;
    red[t] = s;
    __syncthreads();
    for (int off = 1; off < 256; off <<= 1) {
        int u = (t >= off) ? red[t - off] : 0;
        __syncthreads();
        red[t] += u;
        __syncthreads();
    }
    int run = red[t] - s + beg;
    __syncthreads();
    int p = run;
    #pragma unroll
    for (int j = 0; j < 4; j++) {
        int idx = i0 + j;
        int v = (j == 0) ? v0 : (j == 1) ? v1 : (j == 2) ? v2 : v3;
        int node = node0 + idx;
        if (node < N) row[node] = p;
        nh[idx] = p;
        p += v;
    }
    __syncthreads();
    for (int i = beg + t; i < end; i += 256) {
        int2 r = staging[i];
        int dlow = (unsigned)r.x >> 20;
        int pos = atomicAdd(&nh[dlow], 1);
        sedge[pos] = make_int2(r.x & 0xFFFFF, r.y);
    }
}

// ---------- layer 1 GEMM via split-bf16 MFMA (wave = 16 nodes x 64 feats x K=128) ----------
__global__ __launch_bounds__(256) void gemm1_mfma_kernel(
        const float* __restrict__ x,
        const u16* __restrict__ Wt_hi, const u16* __restrict__ Wt_lo,
        const float* __restrict__ att_src, const float* __restrict__ att_dst,
        float* __restrict__ h1, float* __restrict__ a_s, float* __restrict__ a_d, int N) {
    int w = threadIdx.x >> 6, lane = threadIdx.x & 63;
    int m = lane & 15, q = lane >> 4;
    int base = blockIdx.x * 64 + w * 16;
    int nodeA = base + m;                  // A-operand row this lane loads
    bool inA = nodeA < N;
    const float* xrow = x + (size_t)nodeA * FIN;

    v8s ah[4], al[4];                      // A fragments (hi/lo) for 4 k-tiles
    #pragma unroll
    for (int kt = 0; kt < 4; kt++) {
        float xv[8];
        if (inA) {
            const float4* p = (const float4*)(xrow + kt * 32 + q * 8);
            float4 u0 = p[0], u1 = p[1];
            xv[0] = u0.x; xv[1] = u0.y; xv[2] = u0.z; xv[3] = u0.w;
            xv[4] = u1.x; xv[5] = u1.y; xv[6] = u1.z; xv[7] = u1.w;
        } else {
            #pragma unroll
            for (int j = 0; j < 8; j++) xv[j] = 0.f;
        }
        #pragma unroll
        for (int j = 0; j < 8; j++) {
            u16 hb, lb;
            split_bf16(xv[j], hb, lb);
            ah[kt][j] = (short)hb;
            al[kt][j] = (short)lb;
        }
    }

    float ps[4] = {0.f, 0.f, 0.f, 0.f};
    float pd[4] = {0.f, 0.f, 0.f, 0.f};
    #pragma unroll
    for (int ft = 0; ft < 4; ft++) {
        v4f acc = {0.f, 0.f, 0.f, 0.f};
        const u16* bh_base = Wt_hi + (ft * 16 + m) * FIN + q * 8;
        const u16* bl_base = Wt_lo + (ft * 16 + m) * FIN + q * 8;
        #pragma unroll
        for (int kt = 0; kt < 4; kt++) {
            v8s bh = *(const v8s*)(bh_base + kt * 32);
            v8s bl = *(const v8s*)(bl_base + kt * 32);
            acc = __builtin_amdgcn_mfma_f32_16x16x32_bf16(ah[kt], bh, acc, 0, 0, 0);
            acc = __builtin_amdgcn_mfma_f32_16x16x32_bf16(al[kt], bh, acc, 0, 0, 0);
            acc = __builtin_amdgcn_mfma_f32_16x16x32_bf16(ah[kt], bl, acc, 0, 0, 0);
        }
        int f = ft * 16 + m;               // C col = lane&15
        float asf = att_src[f], adf = att_dst[f];
        #pragma unroll
        for (int r = 0; r < 4; r++) {      // C row = q*4 + r
            int node = base + q * 4 + r;
            if (node < N) h1[(size_t)node * H + f] = acc[r];
            ps[r] += acc[r] * asf;
            pd[r] += acc[r] * adf;
        }
    }
    // reduce partial logits across the 16 cols (lanes with same q)
    #pragma unroll
    for (int msk = 1; msk < 16; msk <<= 1) {
        #pragma unroll
        for (int r = 0; r < 4; r++) {
            ps[r] += __shfl_xor(ps[r], msk, 64);
            pd[r] += __shfl_xor(pd[r], msk, 64);
        }
    }
    if (m == 0) {
        #pragma unroll
        for (int r = 0; r < 4; r++) {
            int node = base + q * 4 + r;
            if (node < N) { a_s[node] = ps[r]; a_d[node] = pd[r]; }
        }
    }
}

// ---------- layer 1 aggregation (wave per dst node) + node1 + gemm2 fused ----------
__global__ __launch_bounds__(256) void agg1_kernel(
        const int* __restrict__ row, const int2* __restrict__ sedge,
        const float* __restrict__ scal,
        const float* __restrict__ a_s, const float* __restrict__ a_d,
        const float* __restrict__ h1,
        const float* __restrict__ bias1, const float* __restrict__ W2,
        const float* __restrict__ att_src2, const float* __restrict__ att_dst2,
        float* __restrict__ h2, float* __restrict__ a_s2, float* __restrict__ a_d2,
        int N) {
    int n = (blockIdx.x << 2) + (threadIdx.x >> 6);   // dst node
    int lane = threadIdx.x & 63;
    if (n >= N) return;
    float c1 = scal[1];
    float ad = a_d[n];
    int beg = row[n], end = row[n + 1];
    float den = 0.f, acc = 0.f;
    int i = beg;
    for (; i + 4 <= end; i += 4) {
        int2 e0v = sedge[i], e1v = sedge[i + 1], e2v = sedge[i + 2], e3v = sedge[i + 3];
        int s0 = e0v.x, s1 = e1v.x, s2 = e2v.x, s3 = e3v.x;
        float h0 = h1[(size_t)s0 * H + lane];
        float hA = h1[(size_t)s1 * H + lane];
        float hB = h1[(size_t)s2 * H + lane];
        float hC = h1[(size_t)s3 * H + lane];
        float as0 = a_s[s0], as1 = a_s[s1], as2 = a_s[s2], as3 = a_s[s3];
        float lg0 = as0 + ad + __int_as_float(e0v.y) * c1; lg0 = lg0 > 0.f ? lg0 : NEG_SLOPE * lg0;
        float lg1 = as1 + ad + __int_as_float(e1v.y) * c1; lg1 = lg1 > 0.f ? lg1 : NEG_SLOPE * lg1;
        float lg2 = as2 + ad + __int_as_float(e2v.y) * c1; lg2 = lg2 > 0.f ? lg2 : NEG_SLOPE * lg2;
        float lg3 = as3 + ad + __int_as_float(e3v.y) * c1; lg3 = lg3 > 0.f ? lg3 : NEG_SLOPE * lg3;
        float e0 = __expf(lg0), e1 = __expf(lg1), e2 = __expf(lg2), e3 = __expf(lg3);
        den += (e0 + e1) + (e2 + e3);
        acc += e0 * h0 + e1 * hA + e2 * hB + e3 * hC;
    }
    for (; i < end; i++) {
        int2 ev = sedge[i];
        int s = ev.x;
        float lg = a_s[s] + ad + __int_as_float(ev.y) * c1;
        lg = lg > 0.f ? lg : NEG_SLOPE * lg;
        float ex = __expf(lg);
        den += ex;
        acc += ex * h1[(size_t)s * H + lane];
    }
    // self loop (src = dst = n, edge_attr = mean)
    {
        float lg = a_s[n] + ad + scal[0] * c1;
        lg = lg > 0.f ? lg : NEG_SLOPE * lg;
        float ex = __expf(lg);
        den += ex;
        acc += ex * h1[(size_t)n * H + lane];
    }
    float hr = acc / (den + EPSF) + bias1[lane];
    hr = fmaxf(hr, 0.f);
    // fused gemm2: h2 = hr @ W2  (64 -> 2)
    float p0 = hr * W2[lane * C + 0];
    float p1 = hr * W2[lane * C + 1];
    for (int off = 32; off; off >>= 1) {
        p0 += __shfl_down(p0, off, 64);
        p1 += __shfl_down(p1, off, 64);
    }
    if (lane == 0) {
        h2[(size_t)n * C + 0] = p0;
        h2[(size_t)n * C + 1] = p1;
        a_s2[n] = p0 * att_src2[0] + p1 * att_src2[1];
        a_d2[n] = p0 * att_dst2[0] + p1 * att_dst2[1];
    }
}

// ---------- layer 2 aggregation (wave per dst node, lanes over edges) + log_softmax ----------
__global__ __launch_bounds__(256) void agg2_kernel(
        const int* __restrict__ row, const int2* __restrict__ sedge,
        const float* __restrict__ scal,
        const float* __restrict__ a_s2, const float* __restrict__ a_d2,
        const float* __restrict__ h2, const float* __restrict__ bias2,
        float* __restrict__ out, int N) {
    int n = (blockIdx.x << 2) + (threadIdx.x >> 6);
    int lane = threadIdx.x & 63;
    if (n >= N) return;
    float c2 = scal[2];
    float ad = a_d2[n];
    int beg = row[n], end = row[n + 1];
    float den = 0.f, m0 = 0.f, m1 = 0.f;
    for (int i = beg + lane; i < end; i += 64) {
        int2 ev = sedge[i];
        int s = ev.x;
        float lg = a_s2[s] + ad + __int_as_float(ev.y) * c2;
        lg = lg > 0.f ? lg : NEG_SLOPE * lg;
        float ex = __expf(lg);
        den += ex;
        m0 += ex * h2[(size_t)s * C + 0];
        m1 += ex * h2[(size_t)s * C + 1];
    }
    if (lane == 0) {   // self loop
        float lg = a_s2[n] + ad + scal[0] * c2;
        lg = lg > 0.f ? lg : NEG_SLOPE * lg;
        float ex = __expf(lg);
        den += ex;
        m0 += ex * h2[(size_t)n * C + 0];
        m1 += ex * h2[(size_t)n * C + 1];
    }
    for (int off = 32; off; off >>= 1) {
        den += __shfl_down(den, off, 64);
        m0  += __shfl_down(m0, off, 64);
        m1  += __shfl_down(m1, off, 64);
    }
    if (lane == 0) {
        float dn = den + EPSF;
        float o0 = m0 / dn + bias2[0];
        float o1 = m1 / dn + bias2[1];
        float mx = fmaxf(o0, o1);
        float lse = mx + logf(expf(o0 - mx) + expf(o1 - mx));
        out[(size_t)n * C + 0] = o0 - lse;
        out[(size_t)n * C + 1] = o1 - lse;
    }
}

extern "C" void kernel_launch(void* const* d_in, const int* in_sizes, int n_in,
                              void* d_out, int out_size, void* d_ws, size_t ws_size,
                              hipStream_t stream) {
    const float* x        = (const float*)d_in[0];
    const int*   ei       = (const int*)d_in[1];
    const float* ea       = (const float*)d_in[2];
    const float* W1       = (const float*)d_in[3];
    const float* att_src1 = (const float*)d_in[4];
    const float* att_dst1 = (const float*)d_in[5];
    const float* W_edge1  = (const float*)d_in[6];
    const float* att_edge1= (const float*)d_in[7];
    const float* bias1    = (const float*)d_in[8];
    const float* W2       = (const float*)d_in[9];
    const float* att_src2 = (const float*)d_in[10];
    const float* att_dst2 = (const float*)d_in[11];
    const float* W_edge2  = (const float*)d_in[12];
    const float* att_edge2= (const float*)d_in[13];
    const float* bias2    = (const float*)d_in[14];

    const int N  = in_sizes[0] / FIN;
    const int E  = in_sizes[1] / 2;
    const int* srcp = ei;
    const int* dstp = ei + E;
    const int NBUCK = (N + (1 << BSHIFT) - 1) >> BSHIFT;   // 98 for N=100k

    char* wsb = (char*)d_ws;
    size_t off = 0;
    auto alloc = [&](size_t bytes) { void* p = wsb + off; off += (bytes + 255) & ~size_t(255); return p; };
    int*   bcount = (int*)alloc((size_t)NBUCK_MAX * 4);
    float* sum_ea = (float*)alloc(4);
    size_t zbytes = off;                        // bcount + sum_ea must be zeroed
    int*   bbase  = (int*)alloc((size_t)(NBUCK_MAX + 1) * 4);
    int*   bcursor= (int*)alloc((size_t)NBUCK_MAX * 4);
    int*   row    = (int*)alloc((size_t)(N + 1) * 4);
    int2*  sedge  = (int2*)alloc((size_t)E * 8);
    float* h1     = (float*)alloc((size_t)N * H * 4);
    int2*  staging= (int2*)h1;                  // staging dead before gemm1 writes h1
    u16*   Wt_hi  = (u16*)alloc((size_t)FIN * H * 2);
    u16*   Wt_lo  = (u16*)alloc((size_t)FIN * H * 2);
    float* a_s1   = (float*)alloc((size_t)N * 4);
    float* a_d1   = (float*)alloc((size_t)N * 4);
    float* h2     = (float*)alloc((size_t)N * C * 4);
    float* a_s2   = (float*)alloc((size_t)N * 4);
    float* a_d2   = (float*)alloc((size_t)N * 4);
    float* scal   = (float*)alloc(3 * 4);

    hipMemsetAsync(d_ws, 0, zbytes, stream);

    ea_sum_kernel<<<1024, 256, 0, stream>>>(ea, E, sum_ea);
    scalars_kernel<<<1, 64, 0, stream>>>(sum_ea, E, W_edge1, att_edge1, W_edge2, att_edge2, scal);
    wprep_kernel<<<(FIN * H + 255) / 256, 256, 0, stream>>>(W1, Wt_hi, Wt_lo);
    bcount_kernel<<<256, 256, 0, stream>>>(dstp, E, bcount, NBUCK);
    bscan_kernel<<<1, 1024, 0, stream>>>(bcount, NBUCK, E, bbase, bcursor, row + N);
    stage_kernel<<<(E + CHUNK - 1) / CHUNK, 256, 0, stream>>>(srcp, dstp, ea, E, bcursor, staging, NBUCK);
    bfin_kernel<<<NBUCK, 256, 0, stream>>>(staging, bbase, row, sedge, N);
    gemm1_mfma_kernel<<<(N + 63) / 64, 256, 0, stream>>>(x, Wt_hi, Wt_lo, att_src1, att_dst1,
                                                         h1, a_s1, a_d1, N);
    agg1_kernel<<<(N + 3) / 4, 256, 0, stream>>>(row, sedge, scal, a_s1, a_d1, h1,
                                                 bias1, W2, att_src2, att_dst2,
                                                 h2, a_s2, a_d2, N);
    agg2_kernel<<<(N + 3) / 4, 256, 0, stream>>>(row, sedge, scal, a_s2, a_d2, h2, bias2,
                                                 (float*)d_out, N);
}